// Round 2
// baseline (1712.224 us; speedup 1.0000x reference)
//
#include <hip/hip_runtime.h>
#include <cstdint>

#define VOCAB 100000
#define EMB 300
#define NE 301         // 300 emb dims + 1 bias row (evoke_b)
#define KP 128         // padded h (bf16 elements per p-row)
#define PSTORE 112     // stored p rows per e (7 tiles of 16; p>=100 zero-padded)
#define EKSTRIDE 28672 // bytes per e slab = 112*128*2
#define NP 128         // G row stride (floats)
#define BM 64
#define BTOT 16384

typedef __attribute__((ext_vector_type(8))) short short8;
typedef __attribute__((ext_vector_type(4))) float f32x4;

__device__ __forceinline__ unsigned short f2bf(float f) {
    uint32_t u = __float_as_uint(f);
    uint32_t r = (u + 0x7fffu + ((u >> 16) & 1u)) >> 16;   // RNE
    return (unsigned short)r;
}

// ---------------------------------------------------------------------------
// Prep 1: pack evoke_k (+ evoke_b as e=300) into bf16 [NE][112 p][128 h], no swizzle.
// ---------------------------------------------------------------------------
__global__ __launch_bounds__(256) void k_ekprep(const float* __restrict__ evoke_k,
                                                const float* __restrict__ evoke_b,
                                                unsigned short* __restrict__ ekp) {
    int e = blockIdx.x;            // 0..300
    int tid = threadIdx.x;
    const float* src = (e < EMB) ? (evoke_k + (size_t)e * 10000) : evoke_b;
    uint32_t* dst = (uint32_t*)ekp + (size_t)e * (EKSTRIDE / 4);
#pragma unroll
    for (int i = 0; i < 28; ++i) {
        int d = i * 256 + tid;     // 0..7167
        int p = d >> 6;            // 0..111
        int h2 = d & 63;           // dword within row (h = 2*h2, 2*h2+1)
        uint32_t val = 0;
        if (p < 100 && h2 < 50) {
            float2 s = *(const float2*)(src + p * 100 + 2 * h2);
            val = (uint32_t)f2bf(s.x) | ((uint32_t)f2bf(s.y) << 16);
        }
        dst[d] = val;
    }
}

// ---------------------------------------------------------------------------
// Prep 2: time MLP -> tv, stored bf16 [B][128] (h padded with zeros)
// ---------------------------------------------------------------------------
__global__ __launch_bounds__(256) void k_tv(const float* __restrict__ times,
                                            const float* __restrict__ h1_k,
                                            const float* __restrict__ h1_b,
                                            const float* __restrict__ h2_k,
                                            const float* __restrict__ h2_b,
                                            unsigned short* __restrict__ tvp) {
    __shared__ float h1s[16][100];
    int b0 = blockIdx.x * 16;
    for (int idx = threadIdx.x; idx < 1600; idx += 256) {
        int bb = idx / 100, i = idx - bb * 100;
        h1s[bb][i] = tanhf(times[b0 + bb] * h1_k[i] + h1_b[i]);
    }
    __syncthreads();
    for (int idx = threadIdx.x; idx < 1600; idx += 256) {
        int bb = idx / 100, j = idx - bb * 100;
        float acc = h2_b[j];
        for (int i = 0; i < 100; ++i) acc += h1s[bb][i] * h2_k[i * 100 + j];
        tvp[(size_t)(b0 + bb) * KP + j] = f2bf(tanhf(acc));
    }
    for (int idx = threadIdx.x; idx < 16 * 28; idx += 256) {
        int bb = idx / 28, j = 100 + (idx - bb * 28);
        tvp[(size_t)(b0 + bb) * KP + j] = 0;
    }
}

// ---------------------------------------------------------------------------
// Prep 3: G = last_k last_k^T (padded 128x128), v = last_k last_b, c0 = |last_b|^2.
// Also zeroes d_out (runs before main kernel's atomics).
// ---------------------------------------------------------------------------
__global__ __launch_bounds__(128) void k_gprep(const float* __restrict__ last_k,
                                               const float* __restrict__ last_b,
                                               float* __restrict__ G,
                                               float* __restrict__ vvec,
                                               float* __restrict__ c0,
                                               float* __restrict__ out) {
    int p = blockIdx.x;   // 0..127
    int q = threadIdx.x;  // 0..127
    __shared__ float row[EMB];
    for (int d = q; d < EMB; d += 128) row[d] = (p < 100) ? last_k[p * EMB + d] : 0.f;
    __syncthreads();
    float acc = 0.f;
    if (p < 100 && q < 100) {
        for (int d = 0; d < EMB; ++d) acc += row[d] * last_k[q * EMB + d];
    }
    G[p * NP + q] = acc;
    if (q == 0) {
        float a = 0.f;
        if (p < 100) {
            for (int d = 0; d < EMB; ++d) a += row[d] * last_b[d];
        }
        vvec[p] = a;
        if (p == 0) {
            float s = 0.f;
            for (int d = 0; d < EMB; ++d) s += last_b[d] * last_b[d];
            *c0 = s;
            *out = 0.f;
        }
    }
}

// ---------------------------------------------------------------------------
// Main: 64 batch rows per block, 512 threads = 8 waves = 2 waves/SIMD.
// e-range split across two 4-wave groups (g0: e in [0,152), g1: e in [152,301)).
// EK B-frags loaded global->VGPR (wave-private p range), 3-deep pipelined,
// NO barriers in the e-loop. All 301 emb scalar rows staged once as bf16 in LDS.
// __launch_bounds__(512,1): 1 block/CU -> VGPR cap 256 (the (512,2) variant
// capped at 128 and spilled ~4.3 GB of scratch traffic).
// ---------------------------------------------------------------------------
__global__ __launch_bounds__(512, 1) void k_main(
    const int* __restrict__ targets, const int* __restrict__ contexts,
    const float* __restrict__ labels,
    const float* __restrict__ targetemb, const float* __restrict__ contextemb,
    const unsigned short* __restrict__ ekp, const unsigned short* __restrict__ tvp,
    const float* __restrict__ G, const float* __restrict__ vvec,
    const float* __restrict__ c0p, float* __restrict__ out) {
    extern __shared__ char smem[];
    // loop phase  : embl bf16 [301 e][2 br][64 b] = 77,056 B at smem+0
    // epilogue    : mv_t [64][112] at 0, mv_c at +28672  (57,344 B, aliases embl)
    __shared__ float bsum[8];

    const int tid  = threadIdx.x;
    const int lane = tid & 63;
    const int w    = tid >> 6;       // wave 0..7
    const int wg   = w & 3;          // wave-in-group 0..3
    const int g    = w >> 2;         // e-group 0/1
    const int l15  = lane & 15;
    const int l4   = lane >> 4;      // 0..3
    const int m0   = blockIdx.x * BM;

    unsigned short* embl = (unsigned short*)smem;

    // ---- stationary tv A-frags (bf16): m = l15, k-chunk = ks*32 + l4*8 ----
    short8 afrag[4][4];
#pragma unroll
    for (int mt = 0; mt < 4; ++mt) {
        int bg = m0 + mt * 16 + l15;
#pragma unroll
        for (int ks = 0; ks < 4; ++ks) {
            afrag[mt][ks] = *(const short8*)(tvp + (size_t)bg * KP + ks * 32 + l4 * 8);
        }
    }

    // ---- per-wave B-frag activity + global byte offsets within an e-slab ----
    bool act[2];
    int  loff[2][4];
#pragma unroll
    for (int nt = 0; nt < 2; ++nt) {
        int t = wg * 2 + nt;         // n-tile 0..7; tile 7 doesn't exist (p<112)
        act[nt] = (t < 7);
        int p = t * 16 + l15;
#pragma unroll
        for (int ks = 0; ks < 4; ++ks) {
            loff[nt][ks] = (t < 7) ? (p * 256 + ks * 64 + l4 * 16) : 0;
        }
    }

    auto loadbuf = [&](short8 (&buf)[2][4], int ei) {
        const char* sp = (const char*)ekp + (size_t)ei * EKSTRIDE;
#pragma unroll
        for (int nt = 0; nt < 2; ++nt) {
            if (act[nt]) {
#pragma unroll
                for (int ks = 0; ks < 4; ++ks) {
                    buf[nt][ks] = *(const short8*)(sp + loff[nt][ks]);
                }
            }
        }
    };

    const int e0    = g ? 152 : 0;
    const int niter = g ? 49 : 50;   // 3*niter + 2 == group e-count (152 / 149)

    // ---- issue first pipeline loads before the staging barrier ----
    short8 bufA[2][4], bufB[2][4], bufC[2][4];
    loadbuf(bufA, e0);
    loadbuf(bufB, e0 + 1);

    // ---- stage ALL emb scalars (bf16) once: [301 e][2 br][64 b] ----
    {
        int off    = tid & 127;
        int b      = off & 63;
        int branch = off >> 6;
        int seg    = tid >> 7;                    // 0..3
        int s0 = seg * 76;
        int s1 = (seg == 3) ? 300 : (s0 + 76);    // 76/76/76/72 rows, all %4==0
        const int* idxp   = branch ? contexts : targets;
        const float* base = branch ? contextemb : targetemb;
        const float* row  = base + (size_t)idxp[m0 + b] * EMB;
        for (int e = s0; e + 3 < s1; e += 4) {
            float4 v = *(const float4*)(row + e);
            embl[(e + 0) * 128 + off] = f2bf(v.x);
            embl[(e + 1) * 128 + off] = f2bf(v.y);
            embl[(e + 2) * 128 + off] = f2bf(v.z);
            embl[(e + 3) * 128 + off] = f2bf(v.w);
        }
        if (seg == 3) embl[300 * 128 + off] = 0x3F80;   // bias row e=300 -> 1.0
    }

    f32x4 acc_t[4][2], acc_c[4][2];
    const f32x4 zf = {0.f, 0.f, 0.f, 0.f};
#pragma unroll
    for (int mt = 0; mt < 4; ++mt) {
#pragma unroll
        for (int nt = 0; nt < 2; ++nt) { acc_t[mt][nt] = zf; acc_c[mt][nt] = zf; }
    }

    auto compute = [&](int el, short8 (&buf)[2][4]) {
        // emb scalars for this e (broadcast LDS reads, bf16 -> fp32 unpack)
        float et[4][4], ec[4][4];
#pragma unroll
        for (int mt = 0; mt < 4; ++mt) {
            int row0 = mt * 16 + l4 * 4;
            uint2 dt = *(const uint2*)(embl + el * 128 + row0);
            uint2 dc = *(const uint2*)(embl + el * 128 + 64 + row0);
            et[mt][0] = __uint_as_float(dt.x << 16);
            et[mt][1] = __uint_as_float(dt.x & 0xffff0000u);
            et[mt][2] = __uint_as_float(dt.y << 16);
            et[mt][3] = __uint_as_float(dt.y & 0xffff0000u);
            ec[mt][0] = __uint_as_float(dc.x << 16);
            ec[mt][1] = __uint_as_float(dc.x & 0xffff0000u);
            ec[mt][2] = __uint_as_float(dc.y << 16);
            ec[mt][3] = __uint_as_float(dc.y & 0xffff0000u);
        }
#pragma unroll
        for (int nt = 0; nt < 2; ++nt) {
            if (act[nt]) {
                f32x4 S[4];
#pragma unroll
                for (int mt = 0; mt < 4; ++mt) S[mt] = zf;
#pragma unroll
                for (int ks = 0; ks < 4; ++ks) {
#pragma unroll
                    for (int mt = 0; mt < 4; ++mt) {
                        S[mt] = __builtin_amdgcn_mfma_f32_16x16x32_bf16(
                            afrag[mt][ks], buf[nt][ks], S[mt], 0, 0, 0);
                    }
                }
#pragma unroll
                for (int mt = 0; mt < 4; ++mt) {
#pragma unroll
                    for (int r = 0; r < 4; ++r) {
                        acc_t[mt][nt][r] += et[mt][r] * S[mt][r];
                        acc_c[mt][nt][r] += ec[mt][r] * S[mt][r];
                    }
                }
            }
        }
    };

    __syncthreads();   // embl staged; the only barrier before the epilogue

    // ---- barrier-free 3-deep pipelined e-loop (per-group range) ----
#pragma unroll 1
    for (int i = 0; i < niter; ++i) {
        int base = e0 + 3 * i;
        loadbuf(bufC, base + 2);
        compute(base, bufA);
        loadbuf(bufA, base + 3);
        compute(base + 1, bufB);
        loadbuf(bufB, base + 4);
        compute(base + 2, bufC);
    }
    {
        int base = e0 + 3 * niter;     // g0: 150, g1: 299
        compute(base, bufA);
        compute(base + 1, bufB);       // g1: e=300 (bias row)
    }

    // ---- epilogue: merge the two e-groups through LDS ----
    __syncthreads();
    float* mvt = (float*)smem;              // [64][112]
    float* mvc = (float*)(smem + 28672);    // [64][112]
    if (g == 0) {
#pragma unroll
        for (int mt = 0; mt < 4; ++mt) {
#pragma unroll
            for (int nt = 0; nt < 2; ++nt) {
                if (act[nt]) {
                    int col = (wg * 2 + nt) * 16 + l15;   // 0..111
#pragma unroll
                    for (int r = 0; r < 4; ++r) {
                        int row = mt * 16 + l4 * 4 + r;
                        mvt[row * 112 + col] = acc_t[mt][nt][r];
                        mvc[row * 112 + col] = acc_c[mt][nt][r];
                    }
                }
            }
        }
    }
    __syncthreads();
    if (g == 1) {
#pragma unroll
        for (int mt = 0; mt < 4; ++mt) {
#pragma unroll
            for (int nt = 0; nt < 2; ++nt) {
                if (act[nt]) {
                    int col = (wg * 2 + nt) * 16 + l15;
#pragma unroll
                    for (int r = 0; r < 4; ++r) {
                        int row = mt * 16 + l4 * 4 + r;
                        mvt[row * 112 + col] += acc_t[mt][nt][r];
                        mvc[row * 112 + col] += acc_c[mt][nt][r];
                    }
                }
            }
        }
    }
    __syncthreads();

    int b_loc = tid >> 3;        // 0..63
    int oct   = tid & 7;         // 0..7
    float4 cr[28];
#pragma unroll
    for (int i = 0; i < 28; ++i) cr[i] = *(const float4*)(mvc + b_loc * 112 + i * 4);

    float part = 0.f;
    for (int pp = 0; pp < 14; ++pp) {
        int p = oct * 14 + pp;
        const float4* Grow = (const float4*)(G + p * NP);
        float wq = 0.f;
#pragma unroll 7
        for (int qq = 0; qq < 28; ++qq) {
            float4 gg = Grow[qq];
            float4 m  = cr[qq];
            wq += gg.x * m.x + gg.y * m.y + gg.z * m.z + gg.w * m.w;
        }
        float mtv = mvt[b_loc * 112 + p];
        float mcv = mvc[b_loc * 112 + p];
        part += mtv * wq + vvec[p] * (mtv + mcv);
    }
    part += __shfl_xor(part, 1);
    part += __shfl_xor(part, 2);
    part += __shfl_xor(part, 4);

    float lossv = 0.f;
    if (oct == 0) {
        float logit = part + *c0p;
        float lab = labels[m0 + b_loc];
        lossv = fmaxf(logit, 0.f) - logit * lab + log1pf(expf(-fabsf(logit)));
    }
#pragma unroll
    for (int off = 8; off < 64; off <<= 1) lossv += __shfl_xor(lossv, off);
    if (lane == 0) bsum[w] = lossv;
    __syncthreads();
    if (tid == 0) {
        atomicAdd(out, (bsum[0] + bsum[1] + bsum[2] + bsum[3] +
                        bsum[4] + bsum[5] + bsum[6] + bsum[7]) * (1.0f / 16384.0f));
    }
}

// ---------------------------------------------------------------------------
extern "C" void kernel_launch(void* const* d_in, const int* in_sizes, int n_in,
                              void* d_out, int out_size, void* d_ws, size_t ws_size,
                              hipStream_t stream) {
    const int*   targets    = (const int*)d_in[0];
    const int*   contexts   = (const int*)d_in[1];
    const float* times      = (const float*)d_in[2];
    const float* labels     = (const float*)d_in[3];
    const float* targetemb  = (const float*)d_in[4];
    const float* contextemb = (const float*)d_in[5];
    const float* h1_k       = (const float*)d_in[6];
    const float* h1_b       = (const float*)d_in[7];
    const float* h2_k       = (const float*)d_in[8];
    const float* h2_b       = (const float*)d_in[9];
    const float* evoke_k    = (const float*)d_in[10];
    const float* evoke_b    = (const float*)d_in[11];
    const float* last_k     = (const float*)d_in[12];
    const float* last_b     = (const float*)d_in[13];
    float* out = (float*)d_out;

    char* ws = (char*)d_ws;
    unsigned short* ekp = (unsigned short*)ws;                 // 301*112*128*2 = 8,630,272
    unsigned short* tvp = (unsigned short*)(ws + 8630272);     // 16384*128*2   = 4,194,304
    float* G   = (float*)(ws + 8630272 + 4194304);             // 128*128*4     = 65,536
    float* vv  = (float*)(ws + 8630272 + 4194304 + 65536);     // 128*4
    float* c0  = (float*)(ws + 8630272 + 4194304 + 65536 + 512);

    k_ekprep<<<dim3(NE), dim3(256), 0, stream>>>(evoke_k, evoke_b, ekp);
    k_tv<<<dim3(BTOT / 16), dim3(256), 0, stream>>>(times, h1_k, h1_b, h2_k, h2_b, tvp);
    k_gprep<<<dim3(NP), dim3(128), 0, stream>>>(last_k, last_b, G, vv, c0, out);
    k_main<<<dim3(BTOT / BM), dim3(512), 77056, stream>>>(
        targets, contexts, labels, targetemb, contextemb, ekp, tvp, G, vv, c0, out);
}

// Round 3
// 681.063 us; speedup vs baseline: 2.5140x; 2.5140x over previous
//
#include <hip/hip_runtime.h>
#include <cstdint>

#define VOCAB 100000
#define EMB 300
#define NE 301         // 300 emb dims + 1 bias row (evoke_b)
#define KP 128         // padded h (bf16 elements per p-row)
#define EKSTRIDE 28672 // bytes per e slab = 7 tiles * 4 ks * 1024 B
#define NP 128         // G row stride (floats)
#define BM 64
#define BTOT 16384

typedef __attribute__((ext_vector_type(8))) short short8;
typedef __attribute__((ext_vector_type(4))) float f32x4;

__device__ __forceinline__ unsigned short f2bf(float f) {
    uint32_t u = __float_as_uint(f);
    uint32_t r = (u + 0x7fffu + ((u >> 16) & 1u)) >> 16;   // RNE
    return (unsigned short)r;
}

// ---------------------------------------------------------------------------
// Prep 1: pack evoke_k (+ evoke_b as e=300) into bf16 FRAG-ORDERED layout:
// byte offset = e*EKSTRIDE + ((t*4 + ks)*64 + lane)*16, where the 16 B hold
// ek[p = t*16 + (lane&15)][h = ks*32 + (lane>>4)*8 .. +7]  (zero-padded).
// This makes every k_main B-frag load a single fully-coalesced 1024-B instr.
// ---------------------------------------------------------------------------
__global__ __launch_bounds__(256) void k_ekprep(const float* __restrict__ evoke_k,
                                                const float* __restrict__ evoke_b,
                                                unsigned short* __restrict__ ekp) {
    int e = blockIdx.x;            // 0..300
    const float* src = (e < EMB) ? (evoke_k + (size_t)e * 10000) : evoke_b;
    uint32_t* dst = (uint32_t*)(ekp + (size_t)e * (EKSTRIDE / 2));
#pragma unroll
    for (int it = 0; it < 7; ++it) {
        int c    = it * 256 + threadIdx.x;   // chunk-lane id 0..1791
        int lane = c & 63;
        int ks   = (c >> 6) & 3;
        int t    = c >> 8;                   // 0..6
        int p    = t * 16 + (lane & 15);
        int h0   = ks * 32 + (lane >> 4) * 8;
        uint32_t ov[4] = {0u, 0u, 0u, 0u};
        if (p < 100) {
#pragma unroll
            for (int j = 0; j < 8; ++j) {
                int h = h0 + j;
                float f = (h < 100) ? src[p * 100 + h] : 0.f;
                ov[j >> 1] |= (uint32_t)f2bf(f) << ((j & 1) * 16);
            }
        }
        uint32_t* o = dst + (size_t)c * 4;
        o[0] = ov[0]; o[1] = ov[1]; o[2] = ov[2]; o[3] = ov[3];
    }
}

// ---------------------------------------------------------------------------
// Prep 2: time MLP -> tv, stored bf16 [B][128] (h padded with zeros)
// ---------------------------------------------------------------------------
__global__ __launch_bounds__(256) void k_tv(const float* __restrict__ times,
                                            const float* __restrict__ h1_k,
                                            const float* __restrict__ h1_b,
                                            const float* __restrict__ h2_k,
                                            const float* __restrict__ h2_b,
                                            unsigned short* __restrict__ tvp) {
    __shared__ float h1s[16][100];
    int b0 = blockIdx.x * 16;
    for (int idx = threadIdx.x; idx < 1600; idx += 256) {
        int bb = idx / 100, i = idx - bb * 100;
        h1s[bb][i] = tanhf(times[b0 + bb] * h1_k[i] + h1_b[i]);
    }
    __syncthreads();
    for (int idx = threadIdx.x; idx < 1600; idx += 256) {
        int bb = idx / 100, j = idx - bb * 100;
        float acc = h2_b[j];
        for (int i = 0; i < 100; ++i) acc += h1s[bb][i] * h2_k[i * 100 + j];
        tvp[(size_t)(b0 + bb) * KP + j] = f2bf(tanhf(acc));
    }
    for (int idx = threadIdx.x; idx < 16 * 28; idx += 256) {
        int bb = idx / 28, j = 100 + (idx - bb * 28);
        tvp[(size_t)(b0 + bb) * KP + j] = 0;
    }
}

// ---------------------------------------------------------------------------
// Prep 3: G = last_k last_k^T (padded 128x128), v = last_k last_b, c0 = |last_b|^2.
// Also zeroes d_out (runs before main kernel's atomics).
// ---------------------------------------------------------------------------
__global__ __launch_bounds__(128) void k_gprep(const float* __restrict__ last_k,
                                               const float* __restrict__ last_b,
                                               float* __restrict__ G,
                                               float* __restrict__ vvec,
                                               float* __restrict__ c0,
                                               float* __restrict__ out) {
    int p = blockIdx.x;   // 0..127
    int q = threadIdx.x;  // 0..127
    __shared__ float row[EMB];
    for (int d = q; d < EMB; d += 128) row[d] = (p < 100) ? last_k[p * EMB + d] : 0.f;
    __syncthreads();
    float acc = 0.f;
    if (p < 100 && q < 100) {
        for (int d = 0; d < EMB; ++d) acc += row[d] * last_k[q * EMB + d];
    }
    G[p * NP + q] = acc;
    if (q == 0) {
        float a = 0.f;
        if (p < 100) {
            for (int d = 0; d < EMB; ++d) a += row[d] * last_b[d];
        }
        vvec[p] = a;
        if (p == 0) {
            float s = 0.f;
            for (int d = 0; d < EMB; ++d) s += last_b[d] * last_b[d];
            *c0 = s;
            *out = 0.f;
        }
    }
}

// ---------------------------------------------------------------------------
// Main: 64 batch rows x 112 p per block, 256 threads = 4 waves = 1 wave/SIMD.
// EK B-frags loaded global->VGPR from FRAG-ORDERED ekp (one coalesced 1024-B
// load per frag), 3-deep pipelined, NO barriers in the e-loop. All 301 emb
// scalar rows staged once as bf16 in LDS (77 KB; epilogue aliases it).
// NOTE: 512-thread variants cap at 128 VGPR on this backend and spill ~4.3 GB
// of scratch (rounds 1-2) — keep 256 threads.
// ---------------------------------------------------------------------------
__global__ __launch_bounds__(256, 1) void k_main(
    const int* __restrict__ targets, const int* __restrict__ contexts,
    const float* __restrict__ labels,
    const float* __restrict__ targetemb, const float* __restrict__ contextemb,
    const unsigned short* __restrict__ ekp, const unsigned short* __restrict__ tvp,
    const float* __restrict__ G, const float* __restrict__ vvec,
    const float* __restrict__ c0p, float* __restrict__ out) {
    extern __shared__ char smem[];
    // loop phase  : embl bf16 [301 e][2 br][64 b] = 77,056 B at smem+0
    // epilogue    : mv_t [64][112] at 0, mv_c at +28672  (57,344 B, aliases embl)
    __shared__ float bsum[4];

    const int tid  = threadIdx.x;
    const int lane = tid & 63;
    const int w    = tid >> 6;       // wave 0..3
    const int l15  = lane & 15;
    const int l4   = lane >> 4;      // 0..3
    const int m0   = blockIdx.x * BM;

    unsigned short* embl = (unsigned short*)smem;

    // ---- stationary tv A-frags (bf16): m = l15, k-chunk = ks*32 + l4*8 ----
    short8 afrag[4][4];
#pragma unroll
    for (int mt = 0; mt < 4; ++mt) {
        int bg = m0 + mt * 16 + l15;
#pragma unroll
        for (int ks = 0; ks < 4; ++ks) {
            afrag[mt][ks] = *(const short8*)(tvp + (size_t)bg * KP + ks * 32 + l4 * 8);
        }
    }

    // ---- per-wave B-frag activity + frag-ordered byte offsets within a slab ----
    bool act[2];
    int  loff[2][4];
#pragma unroll
    for (int nt = 0; nt < 2; ++nt) {
        int t = w * 2 + nt;          // n-tile 0..7; tile 7 doesn't exist (p<112)
        act[nt] = (t < 7);
#pragma unroll
        for (int ks = 0; ks < 4; ++ks) {
            loff[nt][ks] = (t < 7) ? (((t * 4 + ks) * 64 + lane) * 16) : 0;
        }
    }

    auto loadbuf = [&](short8 (&buf)[2][4], int ei) {
        const char* sp = (const char*)ekp + (size_t)ei * EKSTRIDE;
#pragma unroll
        for (int nt = 0; nt < 2; ++nt) {
            if (act[nt]) {
#pragma unroll
                for (int ks = 0; ks < 4; ++ks) {
                    buf[nt][ks] = *(const short8*)(sp + loff[nt][ks]);
                }
            }
        }
    };

    // ---- issue first pipeline loads before the staging barrier ----
    short8 bufA[2][4], bufB[2][4], bufC[2][4];
    loadbuf(bufA, 0);
    loadbuf(bufB, 1);

    // ---- stage ALL emb scalars (bf16) once: [301 e][2 br][64 b] ----
    {
        int off    = tid & 127;
        int b      = off & 63;
        int branch = off >> 6;
        int seg    = tid >> 7;                    // 0..1
        int s0 = seg * 152;
        int s1 = seg ? 300 : 152;                 // 152 / 148 rows, both %4==0
        const int* idxp   = branch ? contexts : targets;
        const float* base = branch ? contextemb : targetemb;
        const float* row  = base + (size_t)idxp[m0 + b] * EMB;
        for (int e = s0; e + 3 < s1; e += 4) {
            float4 v = *(const float4*)(row + e);
            embl[(e + 0) * 128 + off] = f2bf(v.x);
            embl[(e + 1) * 128 + off] = f2bf(v.y);
            embl[(e + 2) * 128 + off] = f2bf(v.z);
            embl[(e + 3) * 128 + off] = f2bf(v.w);
        }
        if (seg == 1) embl[300 * 128 + off] = 0x3F80;   // bias row e=300 -> 1.0
    }

    f32x4 acc_t[4][2], acc_c[4][2];
    const f32x4 zf = {0.f, 0.f, 0.f, 0.f};
#pragma unroll
    for (int mt = 0; mt < 4; ++mt) {
#pragma unroll
        for (int nt = 0; nt < 2; ++nt) { acc_t[mt][nt] = zf; acc_c[mt][nt] = zf; }
    }

    auto compute = [&](int el, short8 (&buf)[2][4]) {
        // emb scalars for this e (broadcast LDS reads, bf16 -> fp32 unpack)
        float et[4][4], ec[4][4];
#pragma unroll
        for (int mt = 0; mt < 4; ++mt) {
            int row0 = mt * 16 + l4 * 4;
            uint2 dt = *(const uint2*)(embl + el * 128 + row0);
            uint2 dc = *(const uint2*)(embl + el * 128 + 64 + row0);
            et[mt][0] = __uint_as_float(dt.x << 16);
            et[mt][1] = __uint_as_float(dt.x & 0xffff0000u);
            et[mt][2] = __uint_as_float(dt.y << 16);
            et[mt][3] = __uint_as_float(dt.y & 0xffff0000u);
            ec[mt][0] = __uint_as_float(dc.x << 16);
            ec[mt][1] = __uint_as_float(dc.x & 0xffff0000u);
            ec[mt][2] = __uint_as_float(dc.y << 16);
            ec[mt][3] = __uint_as_float(dc.y & 0xffff0000u);
        }
#pragma unroll
        for (int nt = 0; nt < 2; ++nt) {
            if (act[nt]) {
                f32x4 S[4];
#pragma unroll
                for (int mt = 0; mt < 4; ++mt) S[mt] = zf;
#pragma unroll
                for (int ks = 0; ks < 4; ++ks) {
#pragma unroll
                    for (int mt = 0; mt < 4; ++mt) {
                        S[mt] = __builtin_amdgcn_mfma_f32_16x16x32_bf16(
                            afrag[mt][ks], buf[nt][ks], S[mt], 0, 0, 0);
                    }
                }
#pragma unroll
                for (int mt = 0; mt < 4; ++mt) {
#pragma unroll
                    for (int r = 0; r < 4; ++r) {
                        acc_t[mt][nt][r] += et[mt][r] * S[mt][r];
                        acc_c[mt][nt][r] += ec[mt][r] * S[mt][r];
                    }
                }
            }
        }
    };

    __syncthreads();   // embl staged; the only barrier before the epilogue

    // ---- barrier-free 3-deep pipelined e-loop over all 301 e ----
#pragma unroll 1
    for (int i = 0; i < 100; ++i) {
        int base = 3 * i;
        loadbuf(bufC, base + 2);
        compute(base, bufA);
        loadbuf(bufA, (base + 3 < NE) ? (base + 3) : (NE - 1));
        compute(base + 1, bufB);
        loadbuf(bufB, (base + 4 < NE) ? (base + 4) : (NE - 1));
        compute(base + 2, bufC);
    }
    compute(300, bufA);              // e = 300 (bias row)

    // ---- epilogue ----
    __syncthreads();
    float* mvt = (float*)smem;              // [64][112]
    float* mvc = (float*)(smem + 28672);    // [64][112]
#pragma unroll
    for (int mt = 0; mt < 4; ++mt) {
#pragma unroll
        for (int nt = 0; nt < 2; ++nt) {
            if (act[nt]) {
                int col = (w * 2 + nt) * 16 + l15;   // 0..111
#pragma unroll
                for (int r = 0; r < 4; ++r) {
                    int row = mt * 16 + l4 * 4 + r;
                    mvt[row * 112 + col] = acc_t[mt][nt][r];
                    mvc[row * 112 + col] = acc_c[mt][nt][r];
                }
            }
        }
    }
    __syncthreads();

    int b_loc = tid >> 2;
    int quar  = tid & 3;
    float4 cr[28];
#pragma unroll
    for (int i = 0; i < 28; ++i) cr[i] = *(const float4*)(mvc + b_loc * 112 + i * 4);

    float part = 0.f;
    for (int pp = 0; pp < 28; ++pp) {
        int p = quar * 28 + pp;
        const float4* Grow = (const float4*)(G + p * NP);
        float wq = 0.f;
#pragma unroll 7
        for (int qq = 0; qq < 28; ++qq) {
            float4 g = Grow[qq];
            float4 m = cr[qq];
            wq += g.x * m.x + g.y * m.y + g.z * m.z + g.w * m.w;
        }
        float mtv = mvt[b_loc * 112 + p];
        float mcv = mvc[b_loc * 112 + p];
        part += mtv * wq + vvec[p] * (mtv + mcv);
    }
    part += __shfl_xor(part, 1);
    part += __shfl_xor(part, 2);

    float lossv = 0.f;
    if (quar == 0) {
        float logit = part + *c0p;
        float lab = labels[m0 + b_loc];
        lossv = fmaxf(logit, 0.f) - logit * lab + log1pf(expf(-fabsf(logit)));
    }
#pragma unroll
    for (int off = 4; off < 64; off <<= 1) lossv += __shfl_xor(lossv, off);
    if (lane == 0) bsum[w] = lossv;
    __syncthreads();
    if (tid == 0) {
        atomicAdd(out, (bsum[0] + bsum[1] + bsum[2] + bsum[3]) * (1.0f / 16384.0f));
    }
}

// ---------------------------------------------------------------------------
extern "C" void kernel_launch(void* const* d_in, const int* in_sizes, int n_in,
                              void* d_out, int out_size, void* d_ws, size_t ws_size,
                              hipStream_t stream) {
    const int*   targets    = (const int*)d_in[0];
    const int*   contexts   = (const int*)d_in[1];
    const float* times      = (const float*)d_in[2];
    const float* labels     = (const float*)d_in[3];
    const float* targetemb  = (const float*)d_in[4];
    const float* contextemb = (const float*)d_in[5];
    const float* h1_k       = (const float*)d_in[6];
    const float* h1_b       = (const float*)d_in[7];
    const float* h2_k       = (const float*)d_in[8];
    const float* h2_b       = (const float*)d_in[9];
    const float* evoke_k    = (const float*)d_in[10];
    const float* evoke_b    = (const float*)d_in[11];
    const float* last_k     = (const float*)d_in[12];
    const float* last_b     = (const float*)d_in[13];
    float* out = (float*)d_out;

    char* ws = (char*)d_ws;
    unsigned short* ekp = (unsigned short*)ws;                 // 301*28672 = 8,630,272
    unsigned short* tvp = (unsigned short*)(ws + 8630272);     // 16384*128*2 = 4,194,304
    float* G   = (float*)(ws + 8630272 + 4194304);             // 128*128*4   = 65,536
    float* vv  = (float*)(ws + 8630272 + 4194304 + 65536);     // 128*4
    float* c0  = (float*)(ws + 8630272 + 4194304 + 65536 + 512);

    k_ekprep<<<dim3(NE), dim3(256), 0, stream>>>(evoke_k, evoke_b, ekp);
    k_tv<<<dim3(BTOT / 16), dim3(256), 0, stream>>>(times, h1_k, h1_b, h2_k, h2_b, tvp);
    k_gprep<<<dim3(NP), dim3(128), 0, stream>>>(last_k, last_b, G, vv, c0, out);
    k_main<<<dim3(BTOT / BM), dim3(256), 77056, stream>>>(
        targets, contexts, labels, targetemb, contextemb, ekp, tvp, G, vv, c0, out);
}

// Round 4
// 638.404 us; speedup vs baseline: 2.6820x; 1.0668x over previous
//
#include <hip/hip_runtime.h>
#include <cstdint>

#define VOCAB 100000
#define EMB 300
#define NE 301         // 300 emb dims + 1 bias row (evoke_b)
#define KP 128         // padded h (bf16 elements per p-row)
#define EKSTRIDE 28672 // bytes per e slab = 7 tiles * 4 ks * 1024 B
#define NP 128         // G row stride (floats)
#define BM 32
#define BTOT 16384

typedef __attribute__((ext_vector_type(8))) short short8;
typedef __attribute__((ext_vector_type(4))) float f32x4;

__device__ __forceinline__ unsigned short f2bf(float f) {
    uint32_t u = __float_as_uint(f);
    uint32_t r = (u + 0x7fffu + ((u >> 16) & 1u)) >> 16;   // RNE
    return (unsigned short)r;
}

// ---------------------------------------------------------------------------
// Prep 1: pack evoke_k (+ evoke_b as e=300) into bf16 FRAG-ORDERED layout:
// byte offset = e*EKSTRIDE + ((t*4 + ks)*64 + lane)*16, where the 16 B hold
// ek[p = t*16 + (lane&15)][h = ks*32 + (lane>>4)*8 .. +7]  (zero-padded).
// Every k_main B-frag load is a single fully-coalesced 1024-B instruction.
// ---------------------------------------------------------------------------
__global__ __launch_bounds__(256) void k_ekprep(const float* __restrict__ evoke_k,
                                                const float* __restrict__ evoke_b,
                                                unsigned short* __restrict__ ekp) {
    int e = blockIdx.x;            // 0..300
    const float* src = (e < EMB) ? (evoke_k + (size_t)e * 10000) : evoke_b;
    uint32_t* dst = (uint32_t*)(ekp + (size_t)e * (EKSTRIDE / 2));
#pragma unroll
    for (int it = 0; it < 7; ++it) {
        int c    = it * 256 + threadIdx.x;   // chunk-lane id 0..1791
        int lane = c & 63;
        int ks   = (c >> 6) & 3;
        int t    = c >> 8;                   // 0..6
        int p    = t * 16 + (lane & 15);
        int h0   = ks * 32 + (lane >> 4) * 8;
        uint32_t ov[4] = {0u, 0u, 0u, 0u};
        if (p < 100) {
#pragma unroll
            for (int j = 0; j < 8; ++j) {
                int h = h0 + j;
                float f = (h < 100) ? src[p * 100 + h] : 0.f;
                ov[j >> 1] |= (uint32_t)f2bf(f) << ((j & 1) * 16);
            }
        }
        uint32_t* o = dst + (size_t)c * 4;
        o[0] = ov[0]; o[1] = ov[1]; o[2] = ov[2]; o[3] = ov[3];
    }
}

// ---------------------------------------------------------------------------
// Prep 2: time MLP -> tv, stored bf16 [B][128] (h padded with zeros)
// ---------------------------------------------------------------------------
__global__ __launch_bounds__(256) void k_tv(const float* __restrict__ times,
                                            const float* __restrict__ h1_k,
                                            const float* __restrict__ h1_b,
                                            const float* __restrict__ h2_k,
                                            const float* __restrict__ h2_b,
                                            unsigned short* __restrict__ tvp) {
    __shared__ float h1s[16][100];
    int b0 = blockIdx.x * 16;
    for (int idx = threadIdx.x; idx < 1600; idx += 256) {
        int bb = idx / 100, i = idx - bb * 100;
        h1s[bb][i] = tanhf(times[b0 + bb] * h1_k[i] + h1_b[i]);
    }
    __syncthreads();
    for (int idx = threadIdx.x; idx < 1600; idx += 256) {
        int bb = idx / 100, j = idx - bb * 100;
        float acc = h2_b[j];
        for (int i = 0; i < 100; ++i) acc += h1s[bb][i] * h2_k[i * 100 + j];
        tvp[(size_t)(b0 + bb) * KP + j] = f2bf(tanhf(acc));
    }
    for (int idx = threadIdx.x; idx < 16 * 28; idx += 256) {
        int bb = idx / 28, j = 100 + (idx - bb * 28);
        tvp[(size_t)(b0 + bb) * KP + j] = 0;
    }
}

// ---------------------------------------------------------------------------
// Prep 3: G = last_k last_k^T (padded 128x128), v = last_k last_b, c0 = |last_b|^2.
// Also zeroes d_out (runs before main kernel's atomics).
// ---------------------------------------------------------------------------
__global__ __launch_bounds__(128) void k_gprep(const float* __restrict__ last_k,
                                               const float* __restrict__ last_b,
                                               float* __restrict__ G,
                                               float* __restrict__ vvec,
                                               float* __restrict__ c0,
                                               float* __restrict__ out) {
    int p = blockIdx.x;   // 0..127
    int q = threadIdx.x;  // 0..127
    __shared__ float row[EMB];
    for (int d = q; d < EMB; d += 128) row[d] = (p < 100) ? last_k[p * EMB + d] : 0.f;
    __syncthreads();
    float acc = 0.f;
    if (p < 100 && q < 100) {
        for (int d = 0; d < EMB; ++d) acc += row[d] * last_k[q * EMB + d];
    }
    G[p * NP + q] = acc;
    if (q == 0) {
        float a = 0.f;
        if (p < 100) {
            for (int d = 0; d < EMB; ++d) a += row[d] * last_b[d];
        }
        vvec[p] = a;
        if (p == 0) {
            float s = 0.f;
            for (int d = 0; d < EMB; ++d) s += last_b[d] * last_b[d];
            *c0 = s;
            *out = 0.f;
        }
    }
}

// ---------------------------------------------------------------------------
// Main: 32 batch rows x 112 p per block, 256 threads = 4 waves, 512 blocks ->
// 2 blocks/CU = 2 waves/SIMD.  Per-wave footprint halved vs BM=64 (afrag 32 +
// acc 32 + 3x32 buffers ~ 180 VGPR) so the 3-deep global->VGPR pipeline can
// stay in registers (BM=64 allocated only 160 VGPR and the allocator sank the
// loads, exposing full L2/L3 latency each e).  NO barriers in the e-loop.
// NOTE: 512-thread blocks cap at 128 VGPR on this backend and spill (r1-2).
// ---------------------------------------------------------------------------
__global__ __launch_bounds__(256, 1) void k_main(
    const int* __restrict__ targets, const int* __restrict__ contexts,
    const float* __restrict__ labels,
    const float* __restrict__ targetemb, const float* __restrict__ contextemb,
    const unsigned short* __restrict__ ekp, const unsigned short* __restrict__ tvp,
    const float* __restrict__ G, const float* __restrict__ vvec,
    const float* __restrict__ c0p, float* __restrict__ out) {
    extern __shared__ char smem[];
    // loop phase  : embl bf16 [301 e][2 br][32 b] = 38,528 B at smem+0
    // epilogue    : mv_t [32][112] at 0, mv_c at +14336 (28,672 B, aliases embl)
    __shared__ float bsum[4];

    const int tid  = threadIdx.x;
    const int lane = tid & 63;
    const int w    = tid >> 6;       // wave 0..3
    const int l15  = lane & 15;
    const int l4   = lane >> 4;      // 0..3
    const int m0   = blockIdx.x * BM;

    unsigned short* embl = (unsigned short*)smem;

    // ---- stationary tv A-frags (bf16): m = l15, k-chunk = ks*32 + l4*8 ----
    short8 afrag[2][4];
#pragma unroll
    for (int mt = 0; mt < 2; ++mt) {
        int bg = m0 + mt * 16 + l15;
#pragma unroll
        for (int ks = 0; ks < 4; ++ks) {
            afrag[mt][ks] = *(const short8*)(tvp + (size_t)bg * KP + ks * 32 + l4 * 8);
        }
    }

    // ---- per-wave B-frag activity + frag-ordered byte offsets within a slab ----
    bool act[2];
    int  loff[2][4];
#pragma unroll
    for (int nt = 0; nt < 2; ++nt) {
        int t = w * 2 + nt;          // n-tile 0..7; tile 7 doesn't exist (p<112)
        act[nt] = (t < 7);
#pragma unroll
        for (int ks = 0; ks < 4; ++ks) {
            loff[nt][ks] = (t < 7) ? (((t * 4 + ks) * 64 + lane) * 16) : 0;
        }
    }

    auto loadbuf = [&](short8 (&buf)[2][4], int ei) {
        const char* sp = (const char*)ekp + (size_t)ei * EKSTRIDE;
#pragma unroll
        for (int nt = 0; nt < 2; ++nt) {
            if (act[nt]) {
#pragma unroll
                for (int ks = 0; ks < 4; ++ks) {
                    buf[nt][ks] = *(const short8*)(sp + loff[nt][ks]);
                }
            }
        }
    };

    // ---- issue first pipeline loads before the staging barrier ----
    short8 bufA[2][4], bufB[2][4], bufC[2][4];
    loadbuf(bufA, 0);
    loadbuf(bufB, 1);

    // ---- stage ALL emb scalars (bf16) once: [301 e][2 br][32 b] ----
    {
        int off    = tid & 63;                    // branch*32 + b
        int b      = off & 31;
        int branch = off >> 5;
        int seg    = tid >> 6;                    // 0..3
        int s0 = seg * 76;
        int s1 = (seg == 3) ? 300 : (s0 + 76);    // 76/76/76/72 rows, all %4==0
        const int* idxp   = branch ? contexts : targets;
        const float* base = branch ? contextemb : targetemb;
        const float* row  = base + (size_t)idxp[m0 + b] * EMB;
        for (int e = s0; e + 3 < s1; e += 4) {
            float4 v = *(const float4*)(row + e);
            embl[(e + 0) * 64 + off] = f2bf(v.x);
            embl[(e + 1) * 64 + off] = f2bf(v.y);
            embl[(e + 2) * 64 + off] = f2bf(v.z);
            embl[(e + 3) * 64 + off] = f2bf(v.w);
        }
        if (seg == 3) embl[300 * 64 + off] = 0x3F80;   // bias row e=300 -> 1.0
    }

    f32x4 acc_t[2][2], acc_c[2][2];
    const f32x4 zf = {0.f, 0.f, 0.f, 0.f};
#pragma unroll
    for (int mt = 0; mt < 2; ++mt) {
#pragma unroll
        for (int nt = 0; nt < 2; ++nt) { acc_t[mt][nt] = zf; acc_c[mt][nt] = zf; }
    }

    auto compute = [&](int el, short8 (&buf)[2][4]) {
        // emb scalars for this e (broadcast LDS reads, bf16 -> fp32 unpack)
        float et[2][4], ec[2][4];
#pragma unroll
        for (int mt = 0; mt < 2; ++mt) {
            int row0 = mt * 16 + l4 * 4;
            uint2 dt = *(const uint2*)(embl + el * 64 + row0);
            uint2 dc = *(const uint2*)(embl + el * 64 + 32 + row0);
            et[mt][0] = __uint_as_float(dt.x << 16);
            et[mt][1] = __uint_as_float(dt.x & 0xffff0000u);
            et[mt][2] = __uint_as_float(dt.y << 16);
            et[mt][3] = __uint_as_float(dt.y & 0xffff0000u);
            ec[mt][0] = __uint_as_float(dc.x << 16);
            ec[mt][1] = __uint_as_float(dc.x & 0xffff0000u);
            ec[mt][2] = __uint_as_float(dc.y << 16);
            ec[mt][3] = __uint_as_float(dc.y & 0xffff0000u);
        }
#pragma unroll
        for (int nt = 0; nt < 2; ++nt) {
            if (act[nt]) {
                f32x4 S[2];
#pragma unroll
                for (int mt = 0; mt < 2; ++mt) S[mt] = zf;
#pragma unroll
                for (int ks = 0; ks < 4; ++ks) {
#pragma unroll
                    for (int mt = 0; mt < 2; ++mt) {
                        S[mt] = __builtin_amdgcn_mfma_f32_16x16x32_bf16(
                            afrag[mt][ks], buf[nt][ks], S[mt], 0, 0, 0);
                    }
                }
#pragma unroll
                for (int mt = 0; mt < 2; ++mt) {
#pragma unroll
                    for (int r = 0; r < 4; ++r) {
                        acc_t[mt][nt][r] += et[mt][r] * S[mt][r];
                        acc_c[mt][nt][r] += ec[mt][r] * S[mt][r];
                    }
                }
            }
        }
    };

    __syncthreads();   // embl staged; the only barrier before the epilogue

    // ---- barrier-free 3-deep pipelined e-loop over all 301 e ----
#pragma unroll 1
    for (int i = 0; i < 100; ++i) {
        int base = 3 * i;
        loadbuf(bufC, base + 2);
        compute(base, bufA);
        loadbuf(bufA, (base + 3 < NE) ? (base + 3) : (NE - 1));
        compute(base + 1, bufB);
        loadbuf(bufB, (base + 4 < NE) ? (base + 4) : (NE - 1));
        compute(base + 2, bufC);
    }
    compute(300, bufA);              // e = 300 (bias row)

    // ---- epilogue ----
    __syncthreads();
    float* mvt = (float*)smem;              // [32][112]
    float* mvc = (float*)(smem + 14336);    // [32][112]
#pragma unroll
    for (int mt = 0; mt < 2; ++mt) {
#pragma unroll
        for (int nt = 0; nt < 2; ++nt) {
            if (act[nt]) {
                int col = (w * 2 + nt) * 16 + l15;   // 0..111
#pragma unroll
                for (int r = 0; r < 4; ++r) {
                    int row = mt * 16 + l4 * 4 + r;
                    mvt[row * 112 + col] = acc_t[mt][nt][r];
                    mvc[row * 112 + col] = acc_c[mt][nt][r];
                }
            }
        }
    }
    __syncthreads();

    int b_loc = tid >> 3;        // 0..31
    int oct   = tid & 7;         // 0..7
    float4 cr[28];
#pragma unroll
    for (int i = 0; i < 28; ++i) cr[i] = *(const float4*)(mvc + b_loc * 112 + i * 4);

    float part = 0.f;
    for (int pp = 0; pp < 14; ++pp) {
        int p = oct * 14 + pp;
        const float4* Grow = (const float4*)(G + p * NP);
        float wq = 0.f;
#pragma unroll 7
        for (int qq = 0; qq < 28; ++qq) {
            float4 g = Grow[qq];
            float4 m = cr[qq];
            wq += g.x * m.x + g.y * m.y + g.z * m.z + g.w * m.w;
        }
        float mtv = mvt[b_loc * 112 + p];
        float mcv = mvc[b_loc * 112 + p];
        part += mtv * wq + vvec[p] * (mtv + mcv);
    }
    part += __shfl_xor(part, 1);
    part += __shfl_xor(part, 2);
    part += __shfl_xor(part, 4);

    float lossv = 0.f;
    if (oct == 0) {
        float logit = part + *c0p;
        float lab = labels[m0 + b_loc];
        lossv = fmaxf(logit, 0.f) - logit * lab + log1pf(expf(-fabsf(logit)));
    }
#pragma unroll
    for (int off = 8; off < 64; off <<= 1) lossv += __shfl_xor(lossv, off);
    if (lane == 0) bsum[w] = lossv;
    __syncthreads();
    if (tid == 0) {
        atomicAdd(out, (bsum[0] + bsum[1] + bsum[2] + bsum[3]) * (1.0f / 16384.0f));
    }
}

// ---------------------------------------------------------------------------
extern "C" void kernel_launch(void* const* d_in, const int* in_sizes, int n_in,
                              void* d_out, int out_size, void* d_ws, size_t ws_size,
                              hipStream_t stream) {
    const int*   targets    = (const int*)d_in[0];
    const int*   contexts   = (const int*)d_in[1];
    const float* times      = (const float*)d_in[2];
    const float* labels     = (const float*)d_in[3];
    const float* targetemb  = (const float*)d_in[4];
    const float* contextemb = (const float*)d_in[5];
    const float* h1_k       = (const float*)d_in[6];
    const float* h1_b       = (const float*)d_in[7];
    const float* h2_k       = (const float*)d_in[8];
    const float* h2_b       = (const float*)d_in[9];
    const float* evoke_k    = (const float*)d_in[10];
    const float* evoke_b    = (const float*)d_in[11];
    const float* last_k     = (const float*)d_in[12];
    const float* last_b     = (const float*)d_in[13];
    float* out = (float*)d_out;

    char* ws = (char*)d_ws;
    unsigned short* ekp = (unsigned short*)ws;                 // 301*28672 = 8,630,272
    unsigned short* tvp = (unsigned short*)(ws + 8630272);     // 16384*128*2 = 4,194,304
    float* G   = (float*)(ws + 8630272 + 4194304);             // 128*128*4   = 65,536
    float* vv  = (float*)(ws + 8630272 + 4194304 + 65536);     // 128*4
    float* c0  = (float*)(ws + 8630272 + 4194304 + 65536 + 512);

    k_ekprep<<<dim3(NE), dim3(256), 0, stream>>>(evoke_k, evoke_b, ekp);
    k_tv<<<dim3(BTOT / 16), dim3(256), 0, stream>>>(times, h1_k, h1_b, h2_k, h2_b, tvp);
    k_gprep<<<dim3(NP), dim3(128), 0, stream>>>(last_k, last_b, G, vv, c0, out);
    k_main<<<dim3(BTOT / BM), dim3(256), 38528, stream>>>(
        targets, contexts, labels, targetemb, contextemb, ekp, tvp, G, vv, c0, out);
}